// Round 3
// baseline (161.385 us; speedup 1.0000x reference)
//
#include <hip/hip_runtime.h>

#define D_FEAT 128
#define WAVE 64
// Split-D: table stored as 2 contiguous halves of 64 channels (128 B bf16 each).
// Phase p gathers only half p -> per-phase L2 working set 12.8 MB instead of
// 25.6 MB.

typedef float f32x4 __attribute__((ext_vector_type(4)));

__device__ __forceinline__ unsigned short f32_to_bf16_rn(float f) {
    unsigned int u = __float_as_uint(f);
    unsigned int r = u + 0x7fffu + ((u >> 16) & 1u);   // round-to-nearest-even
    return (unsigned short)(r >> 16);
}

__device__ __forceinline__ void acc8(float (&acc)[8], uint4 u) {
    acc[0] += __uint_as_float(u.x << 16);
    acc[1] += __uint_as_float(u.x & 0xffff0000u);
    acc[2] += __uint_as_float(u.y << 16);
    acc[3] += __uint_as_float(u.y & 0xffff0000u);
    acc[4] += __uint_as_float(u.z << 16);
    acc[5] += __uint_as_float(u.z & 0xffff0000u);
    acc[6] += __uint_as_float(u.w << 16);
    acc[7] += __uint_as_float(u.w & 0xffff0000u);
}

// Fused pre-pass: blocks [0, grid_c) convert fp32->bf16 into the SPLIT-HALF
// layout (channels 0-63 of all nodes, then 64-127), plus a zero row per half
// at node index n_nodes; blocks [grid_c, ...) build CSR row offsets.
__global__ void prep_kernel(const float* __restrict__ feats,
                            unsigned short* __restrict__ tbl,
                            int n_elems, int total, int half_elems,
                            const int* __restrict__ rids,
                            int* __restrict__ row_start,
                            int n_edges, int n_rows, int grid_c) {
    if ((int)blockIdx.x < grid_c) {
        int i = (blockIdx.x * blockDim.x + threadIdx.x) * 8;
        if (i >= total) return;
        int node = i >> 7;          // feature row
        int c    = i & 127;         // channel of first elem (multiple of 8)
        int dst  = (c >> 6) * half_elems + (node << 6) + (c & 63);
        uint4 o;
        if (i < n_elems) {
            float4 a = *(const float4*)(feats + i);
            float4 b = *(const float4*)(feats + i + 4);
            o.x = (unsigned)f32_to_bf16_rn(a.x) | ((unsigned)f32_to_bf16_rn(a.y) << 16);
            o.y = (unsigned)f32_to_bf16_rn(a.z) | ((unsigned)f32_to_bf16_rn(a.w) << 16);
            o.z = (unsigned)f32_to_bf16_rn(b.x) | ((unsigned)f32_to_bf16_rn(b.y) << 16);
            o.w = (unsigned)f32_to_bf16_rn(b.z) | ((unsigned)f32_to_bf16_rn(b.w) << 16);
        } else {
            o.x = o.y = o.z = o.w = 0u;   // zero row (node == n_nodes)
        }
        *(uint4*)(tbl + dst) = o;
    } else {
        int e = (blockIdx.x - grid_c) * blockDim.x + threadIdx.x;
        if (e >= n_edges) return;
        int r_cur  = rids[e];
        int r_prev = (e == 0) ? -1 : rids[e - 1];
        for (int r = r_prev + 1; r <= r_cur; ++r) row_start[r] = e;
        if (e == n_edges - 1) {
            for (int r = r_cur + 1; r <= n_rows; ++r) row_start[r] = n_edges;
        }
    }
}

// One wave per (row, channel-half). Half-row = 128 B -> 8 lanes x 16 B per
// edge; one wave64 load gathers EIGHT rows. Full loop (step 32): ids from ONE
// nt wave load + __shfl -> 4 unpredicated gathers in flight (4 KB/wave).
// Phase = gw >= n_rows selects which contiguous 12.8 MB table half is read,
// so concurrently-running blocks share a halved L2 working set.
__global__ void __launch_bounds__(256)
mean_agg_kernel(const uint4* __restrict__ tbl4,
                const int* __restrict__ nids,
                const int* __restrict__ row_start,
                float* __restrict__ out,
                int n_rows, int zero_row, int half_u4) {
    int gw   = (blockIdx.x * blockDim.x + threadIdx.x) >> 6;
    int lane = threadIdx.x & (WAVE - 1);
    int pass = (gw >= n_rows) ? 1 : 0;
    int wave = gw - pass * n_rows;
    if (wave >= n_rows) return;

    const int oct = lane >> 3;     // 0..7: edge slot within a group of 8
    const int sub = lane & 7;      // uint4 slot within the 128 B half-row

    const uint4* __restrict__ tb = tbl4 + (size_t)pass * (size_t)half_u4;

    int lo = row_start[wave];
    int hi = row_start[wave + 1];

    float acc[8];
    #pragma unroll
    for (int k = 0; k < 8; ++k) acc[k] = 0.f;

    int e = lo;
    // full loop: 32 edges, ids via one nt wave load + shuffle, 4 gathers in flight
    for (; e + 32 <= hi; e += 32) {
        int myid = __builtin_nontemporal_load(nids + e + (lane & 31));
        uint4 u[4];
        #pragma unroll
        for (int g = 0; g < 4; ++g) {
            int nid = __shfl(myid, 8 * g + oct, WAVE);
            u[g] = tb[((unsigned)nid << 3) + (unsigned)sub];
        }
        #pragma unroll
        for (int g = 0; g < 4; ++g) acc8(acc, u[g]);
    }
    // remainder: up to 4 clamped 8-edge blocks (wave-uniform branches)
    #pragma unroll
    for (int g = 0; g < 4; ++g) {
        if (e + 8 * g < hi) {
            int idx = e + 8 * g + oct;
            int idc = idx < hi ? idx : hi - 1;
            int nid = nids[idc];
            nid = idx < hi ? nid : zero_row;
            uint4 u = tb[((unsigned)nid << 3) + (unsigned)sub];
            acc8(acc, u);
        }
    }

    // fold the eight 8-lane accumulators (xor 8, 16, 32): afterwards every
    // lane with the same (lane&7) holds identical fully-summed acc[0..7]
    #pragma unroll
    for (int k = 0; k < 8; ++k) {
        acc[k] += __shfl_xor(acc[k], 8, WAVE);
        acc[k] += __shfl_xor(acc[k], 16, WAVE);
        acc[k] += __shfl_xor(acc[k], 32, WAVE);
    }

    int deg = hi - lo;
    float inv = 1.0f / (float)(deg > 0 ? deg : 1);

    // redistribute: lane m (<16) writes channels [4m, 4m+4) of this half.
    // Channel 4m+k lives in source lane srcl = m>>1 as acc[(m&1)*4 + k].
    // Shuffle BOTH halves from srcl and select on the DESTINATION side
    // (selecting pre-shuffle would use the source's parity -> wrong).
    int srcl = (lane & 15) >> 1;
    float o[4];
    #pragma unroll
    for (int k = 0; k < 4; ++k) {
        float vlo = __shfl(acc[k],     srcl, WAVE);
        float vhi = __shfl(acc[4 + k], srcl, WAVE);
        o[k] = ((lane & 1) ? vhi : vlo) * inv;
    }
    if (lane < 16) {
        f32x4 st;
        st.x = o[0]; st.y = o[1]; st.z = o[2]; st.w = o[3];
        __builtin_nontemporal_store(
            st, (f32x4*)(out + (size_t)wave * D_FEAT + pass * 64 + lane * 4));
    }
}

extern "C" void kernel_launch(void* const* d_in, const int* in_sizes, int n_in,
                              void* d_out, int out_size, void* d_ws, size_t ws_size,
                              hipStream_t stream) {
    const float* feats = (const float*)d_in[0];
    const int* nids    = (const int*)d_in[1];
    const int* rids    = (const int*)d_in[2];
    float* out         = (float*)d_out;

    int n_feat_elems = in_sizes[0];
    int n_nodes      = n_feat_elems / D_FEAT;
    int n_edges      = in_sizes[1];
    int n_rows       = out_size / D_FEAT;

    // ws layout: [bf16 table, 2 halves x (n_nodes+1) x 64ch][row_start]
    unsigned short* tbl = (unsigned short*)d_ws;
    size_t tbl_bytes = (size_t)(n_nodes + 1) * D_FEAT * sizeof(unsigned short);
    tbl_bytes = (tbl_bytes + 255) & ~(size_t)255;
    int* row_start = (int*)((char*)d_ws + tbl_bytes);

    const int BLOCK = 256;

    int half_elems = (n_nodes + 1) * 64;        // bf16 elems per half
    int half_u4    = (n_nodes + 1) * 8;         // uint4 per half

    int total_tbl = (n_nodes + 1) * D_FEAT;
    int grid_c = ((total_tbl + 7) / 8 + BLOCK - 1) / BLOCK;
    int grid_b = (n_edges + BLOCK - 1) / BLOCK;
    prep_kernel<<<grid_c + grid_b, BLOCK, 0, stream>>>(feats, tbl, n_feat_elems,
                                                       total_tbl, half_elems,
                                                       rids, row_start,
                                                       n_edges, n_rows, grid_c);

    int waves_per_block = BLOCK / WAVE;
    int total_waves = 2 * n_rows;               // 2 channel-half phases
    int grid_a = (total_waves + waves_per_block - 1) / waves_per_block;
    mean_agg_kernel<<<grid_a, BLOCK, 0, stream>>>((const uint4*)tbl, nids, row_start,
                                                  out, n_rows, n_nodes, half_u4);
}

// Round 4
// 154.358 us; speedup vs baseline: 1.0455x; 1.0455x over previous
//
#include <hip/hip_runtime.h>

#define D_FEAT 128
#define WAVE 64

typedef float f32x4 __attribute__((ext_vector_type(4)));

__device__ __forceinline__ unsigned short f32_to_bf16_rn(float f) {
    unsigned int u = __float_as_uint(f);
    unsigned int r = u + 0x7fffu + ((u >> 16) & 1u);   // round-to-nearest-even
    return (unsigned short)(r >> 16);
}

__device__ __forceinline__ void acc8(float (&acc)[8], uint4 u) {
    acc[0] += __uint_as_float(u.x << 16);
    acc[1] += __uint_as_float(u.x & 0xffff0000u);
    acc[2] += __uint_as_float(u.y << 16);
    acc[3] += __uint_as_float(u.y & 0xffff0000u);
    acc[4] += __uint_as_float(u.z << 16);
    acc[5] += __uint_as_float(u.z & 0xffff0000u);
    acc[6] += __uint_as_float(u.w << 16);
    acc[7] += __uint_as_float(u.w & 0xffff0000u);
}

// Fused pre-pass: blocks [0, grid_c) convert fp32->bf16 table (8 elems/thread,
// plus appended zero row at index n_nodes); blocks [grid_c, grid_c+grid_b)
// build CSR row offsets from the sorted row_ids.
__global__ void prep_kernel(const float* __restrict__ feats,
                            unsigned short* __restrict__ tbl,
                            int n_elems, int total,
                            const int* __restrict__ rids,
                            int* __restrict__ row_start,
                            int n_edges, int n_rows, int grid_c) {
    if ((int)blockIdx.x < grid_c) {
        int i = (blockIdx.x * blockDim.x + threadIdx.x) * 8;
        if (i >= total) return;
        if (i + 8 <= n_elems) {
            float4 a = *(const float4*)(feats + i);
            float4 b = *(const float4*)(feats + i + 4);
            uint4 o;
            o.x = (unsigned)f32_to_bf16_rn(a.x) | ((unsigned)f32_to_bf16_rn(a.y) << 16);
            o.y = (unsigned)f32_to_bf16_rn(a.z) | ((unsigned)f32_to_bf16_rn(a.w) << 16);
            o.z = (unsigned)f32_to_bf16_rn(b.x) | ((unsigned)f32_to_bf16_rn(b.y) << 16);
            o.w = (unsigned)f32_to_bf16_rn(b.z) | ((unsigned)f32_to_bf16_rn(b.w) << 16);
            *(uint4*)(tbl + i) = o;
        } else {
            for (int k = 0; k < 8 && i + k < total; ++k)
                tbl[i + k] = (i + k < n_elems) ? f32_to_bf16_rn(feats[i + k])
                                               : (unsigned short)0;
        }
    } else {
        int e = (blockIdx.x - grid_c) * blockDim.x + threadIdx.x;
        if (e >= n_edges) return;
        int r_cur  = rids[e];
        int r_prev = (e == 0) ? -1 : rids[e - 1];
        for (int r = r_prev + 1; r <= r_cur; ++r) row_start[r] = e;
        if (e == n_edges - 1) {
            for (int r = r_cur + 1; r <= n_rows; ++r) row_start[r] = n_edges;
        }
    }
}

// One wave per output row. bf16 row = 256 B -> quarter-wave (16 lanes x 16 B)
// per edge; one wave64 load gathers FOUR rows. Full loop (step 32): ids come
// from ONE wave nt load + __shfl -> 8 unpredicated gathers issue back-to-back
// (8 KB in flight/wave). The NEXT iteration's id load is issued before the
// current unpack (cuts the serial id->shfl->gather chain out of the loop
// critical path). Streaming accesses (nids, out) carry nontemporal hints so
// they do not evict table lines from L2. Remainder: <=2 wave-uniform clamped
// step-16 blocks, padded lanes hit the L1-resident zero row.
__global__ void __launch_bounds__(256)
mean_agg_kernel(const uint4* __restrict__ tbl4,
                const int* __restrict__ nids,
                const int* __restrict__ row_start,
                float* __restrict__ out,
                int n_rows, int zero_row) {
    int wave = (blockIdx.x * blockDim.x + threadIdx.x) >> 6;
    int lane = threadIdx.x & (WAVE - 1);
    if (wave >= n_rows) return;

    const int q   = lane >> 4;     // quarter 0..3 -> which edge of a group of 4
    const int sub = lane & 15;     // uint4 slot within the 256 B row

    int lo = row_start[wave];
    int hi = row_start[wave + 1];

    float acc[8];
    #pragma unroll
    for (int k = 0; k < 8; ++k) acc[k] = 0.f;

    int e = lo;
    // software-pipelined full loop: 32 edges/iter
    int myid = (e + 32 <= hi) ? __builtin_nontemporal_load(nids + e + (lane & 31)) : 0;
    for (; e + 32 <= hi; ) {
        uint4 u[8];
        #pragma unroll
        for (int g = 0; g < 8; ++g) {
            int nid = __shfl(myid, 4 * g + q, WAVE);
            u[g] = tbl4[((unsigned)nid << 4) + (unsigned)sub];
        }
        e += 32;
        if (e + 32 <= hi)          // prefetch next ids before unpacking current
            myid = __builtin_nontemporal_load(nids + e + (lane & 31));
        #pragma unroll
        for (int g = 0; g < 8; ++g) acc8(acc, u[g]);
    }
    // remainder: up to 2 clamped step-16 blocks (wave-uniform branches)
    #pragma unroll
    for (int half_blk = 0; half_blk < 2; ++half_blk) {
        if (e < hi) {
            #pragma unroll
            for (int g = 0; g < 4; ++g) {
                int idx = e + 4 * g + q;
                int idc = idx < hi ? idx : hi - 1;
                int nid = nids[idc];
                nid = idx < hi ? nid : zero_row;
                uint4 u = tbl4[((unsigned)nid << 4) + (unsigned)sub];
                acc8(acc, u);
            }
            e += 16;
        }
    }

    // fold the four quarter-wave accumulators (xor 16, then 32)
    #pragma unroll
    for (int k = 0; k < 8; ++k) {
        acc[k] += __shfl_xor(acc[k], 16, WAVE);
        acc[k] += __shfl_xor(acc[k], 32, WAVE);
    }

    int deg = hi - lo;
    float inv = 1.0f / (float)(deg > 0 ? deg : 1);

    // lanes 0-31 each store one float4 -> one coalesced 512 B row write (nt)
    if (q < 2) {
        f32x4 o;
        o.x = (q == 0 ? acc[0] : acc[4]) * inv;
        o.y = (q == 0 ? acc[1] : acc[5]) * inv;
        o.z = (q == 0 ? acc[2] : acc[6]) * inv;
        o.w = (q == 0 ? acc[3] : acc[7]) * inv;
        __builtin_nontemporal_store(
            o, (f32x4*)(out + (size_t)wave * D_FEAT + sub * 8 + q * 4));
    }
}

extern "C" void kernel_launch(void* const* d_in, const int* in_sizes, int n_in,
                              void* d_out, int out_size, void* d_ws, size_t ws_size,
                              hipStream_t stream) {
    const float* feats = (const float*)d_in[0];
    const int* nids    = (const int*)d_in[1];
    const int* rids    = (const int*)d_in[2];
    float* out         = (float*)d_out;

    int n_feat_elems = in_sizes[0];
    int n_nodes      = n_feat_elems / D_FEAT;
    int n_edges      = in_sizes[1];
    int n_rows       = out_size / D_FEAT;

    // ws layout: [bf16 table, (n_nodes+1) rows incl. zero row][row_start]
    unsigned short* tbl = (unsigned short*)d_ws;
    size_t tbl_bytes = (size_t)(n_nodes + 1) * D_FEAT * sizeof(unsigned short);
    tbl_bytes = (tbl_bytes + 255) & ~(size_t)255;
    int* row_start = (int*)((char*)d_ws + tbl_bytes);

    const int BLOCK = 256;

    int total_tbl = (n_nodes + 1) * D_FEAT;
    int grid_c = ((total_tbl + 7) / 8 + BLOCK - 1) / BLOCK;
    int grid_b = (n_edges + BLOCK - 1) / BLOCK;
    prep_kernel<<<grid_c + grid_b, BLOCK, 0, stream>>>(feats, tbl, n_feat_elems,
                                                       total_tbl, rids, row_start,
                                                       n_edges, n_rows, grid_c);

    int waves_per_block = BLOCK / WAVE;
    int grid_a = (n_rows + waves_per_block - 1) / waves_per_block;
    mean_agg_kernel<<<grid_a, BLOCK, 0, stream>>>((const uint4*)tbl, nids, row_start,
                                                  out, n_rows, n_nodes);
}